// Round 7
// baseline (1050.643 us; speedup 1.0000x reference)
//
#include <hip/hip_runtime.h>
#include <stdint.h>

#define B_ 4
#define D_ 256
#define N_ 4096
#define K_ 8192
#define Q_ (B_*N_)   // 16384 queries

#define MARGIN 1.0f   // >= 2*E; realistic worst-case f16-approx error E ~0.05

typedef __attribute__((ext_vector_type(8))) _Float16 f16x8;
typedef __attribute__((ext_vector_type(4))) _Float16 f16x4;
typedef __attribute__((ext_vector_type(16))) float f32x16;

__device__ __forceinline__ unsigned enc_sort(float f) {
  unsigned u = __float_as_uint(f);
  return u ^ ((unsigned)(((int)u) >> 31) | 0x80000000u);
}
__device__ __forceinline__ float dec_sort(unsigned u) {
  unsigned v = (u & 0x80000000u) ? (u ^ 0x80000000u) : ~u;
  return __uint_as_float(v);
}

// async global->LDS, 16B per lane; LDS dest is wave-uniform base + lane*16
__device__ __forceinline__ void gl_lds16(const void* g, void* l) {
  __builtin_amdgcn_global_load_lds(
      (const __attribute__((address_space(1))) unsigned int*)g,
      (__attribute__((address_space(3))) unsigned int*)l, 16, 0, 0);
}

// Transpose x [B,D,N] -> xh/xl [Q,D] f16 hi/lo split (x = hi + lo to ~22 bits).
__global__ void prep_x_kernel(const float* __restrict__ x,
                              _Float16* __restrict__ xh,
                              _Float16* __restrict__ xl) {
  __shared__ float tile[64][65];
  int b = blockIdx.z;
  int d0 = blockIdx.y * 64;
  int n0 = blockIdx.x * 64;
  int tid = threadIdx.x;

  int rr = tid >> 4;
  int rc = (tid & 15) * 4;
  const float* xp = x + ((size_t)b * D_ + d0) * N_ + n0;
#pragma unroll
  for (int p = 0; p < 4; ++p) {
    float4 v = *(const float4*)(xp + (size_t)(rr + 16 * p) * N_ + rc);
    tile[rr + 16 * p][rc + 0] = v.x;
    tile[rr + 16 * p][rc + 1] = v.y;
    tile[rr + 16 * p][rc + 2] = v.z;
    tile[rr + 16 * p][rc + 3] = v.w;
  }
  __syncthreads();

  int nr = tid >> 3;
  int dc = tid & 7;
#pragma unroll
  for (int p = 0; p < 2; ++p) {
    int nn = nr + 32 * p;
    f16x8 h8, l8;
#pragma unroll
    for (int j = 0; j < 8; ++j) {
      float v = tile[dc * 8 + j][nn];
      _Float16 h = (_Float16)v;
      h8[j] = h;
      l8[j] = (_Float16)(v - (float)h);
    }
    size_t q = (size_t)b * N_ + n0 + nn;
    *(f16x8*)(xh + q * D_ + d0 + dc * 8) = h8;   // d0 restored (round-6 bug)
    *(f16x8*)(xl + q * D_ + d0 + dc * 8) = l8;
  }
}

// e [K,D] -> eh f16; e2h = 0.5*||e_k||^2 fp32; init thrmin/keys/cnt.
__global__ void prep_e_kernel(const float* __restrict__ e,
                              _Float16* __restrict__ eh,
                              float* __restrict__ e2h,
                              unsigned* __restrict__ thrmin,
                              unsigned long long* __restrict__ keys,
                              unsigned* __restrict__ cnt) {
  int tid = threadIdx.x;
  int g = blockIdx.x * 256 + tid;
  if (g < Q_) { thrmin[g] = 0xFFFFFFFFu; keys[g] = ~0ull; }
  if (g == 0) *cnt = 0u;
  int k = blockIdx.x * 8 + (tid >> 5);
  int d = (tid & 31) * 8;
  const float* ep = e + (size_t)k * D_ + d;
  float4 v0 = *(const float4*)(ep);
  float4 v1 = *(const float4*)(ep + 4);
  float vv[8] = {v0.x, v0.y, v0.z, v0.w, v1.x, v1.y, v1.z, v1.w};
  f16x8 h8;
  float s = 0.f;
#pragma unroll
  for (int j = 0; j < 8; ++j) {
    h8[j] = (_Float16)vv[j];
    s += vv[j] * vv[j];
  }
  *(f16x8*)(eh + (size_t)k * D_ + d) = h8;
#pragma unroll
  for (int off = 16; off > 0; off >>= 1) s += __shfl_xor(s, off, 64);
  if ((tid & 31) == 0) e2h[k] = 0.5f * s;
}

// Pass 0: approx min over a 2048-code subset -> thrmin[q] (sortable u32).
__global__ __launch_bounds__(256, 2) void pass0_kernel(
    const _Float16* __restrict__ xh, const _Float16* __restrict__ eh,
    const float* __restrict__ e2h, unsigned* __restrict__ thrmin) {
  __shared__ __attribute__((aligned(16))) _Float16 Bs[2][32 * 256];
  const int tid = threadIdx.x;
  const int w = tid >> 6, lane = tid & 63;
  const int l = lane & 31, hi = lane >> 5;
  const int qt = blockIdx.x >> 3, ks8 = blockIdx.x & 7;
  const int q0 = qt * 256, kbase = ks8 * 256;
  const int qw = q0 + w * 64;

  f16x8 ah[2][16];
#pragma unroll
  for (int mb = 0; mb < 2; ++mb) {
    const _Float16* pa = xh + (size_t)(qw + mb * 32 + l) * D_ + hi * 8;
#pragma unroll
    for (int k16 = 0; k16 < 16; ++k16)
      ah[mb][k16] = *(const f16x8*)(pa + k16 * 16);
  }

  float rmin[2][16];
#pragma unroll
  for (int mb = 0; mb < 2; ++mb)
#pragma unroll
    for (int r = 0; r < 16; ++r) rmin[mb][r] = __builtin_inff();

  auto stage = [&](int ch, int buf) {
    const int kc = kbase + ch * 32;
#pragma unroll
    for (int p = 0; p < 4; ++p) {
      const int c0 = w * 8 + p * 2;
      const int c = c0 + hi;
      const int g = l ^ (c & 31);
      gl_lds16(eh + (size_t)(kc + c) * D_ + g * 8, &Bs[buf][c0 * 256]);
    }
  };
  stage(0, 0);

#pragma unroll 1
  for (int ch = 0; ch < 8; ++ch) {
    const int buf = ch & 1;
    __syncthreads();
    if (ch + 1 < 8) stage(ch + 1, buf ^ 1);
    const int kc = kbase + ch * 32;
    const float c2 = e2h[kc + l];
    f32x16 acc0, acc1;
#pragma unroll
    for (int r = 0; r < 16; ++r) { acc0[r] = 0.f; acc1[r] = 0.f; }
#pragma unroll
    for (int ks = 0; ks < 16; ++ks) {
      f16x8 bh = *(const f16x8*)&Bs[buf][l * 256 + (((ks * 2 + hi) ^ l) * 8)];
      acc0 = __builtin_amdgcn_mfma_f32_32x32x16_f16(ah[0][ks], bh, acc0, 0, 0, 0);
      acc1 = __builtin_amdgcn_mfma_f32_32x32x16_f16(ah[1][ks], bh, acc1, 0, 0, 0);
    }
#pragma unroll
    for (int r = 0; r < 16; ++r) {
      float s0 = c2 - acc0[r]; if (s0 < rmin[0][r]) rmin[0][r] = s0;
      float s1 = c2 - acc1[r]; if (s1 < rmin[1][r]) rmin[1][r] = s1;
    }
  }

#pragma unroll
  for (int mb = 0; mb < 2; ++mb)
#pragma unroll
    for (int r = 0; r < 16; ++r) {
      float bv = rmin[mb][r];
#pragma unroll
      for (int xm = 1; xm <= 16; xm <<= 1) {
        float ov = __shfl_xor(bv, xm, 64);
        bv = ov < bv ? ov : bv;
      }
      if (l == 0) {
        const int row = (r & 3) + 8 * (r >> 2) + 4 * hi;
        atomicMin(thrmin + qw + mb * 32 + row, enc_sort(bv));
      }
    }
}

// Pass 1: full K scan, f16 hi-term MFMA; emit (q,k) with s~ <= thr[q]+MARGIN.
// block = 256 q x 1024 codes (K-split 8), 4 waves x M=64; grid 512 -> 2 blk/CU.
__global__ __launch_bounds__(256, 2) void pass1_kernel(
    const _Float16* __restrict__ xh, const _Float16* __restrict__ eh,
    const float* __restrict__ e2h, const unsigned* __restrict__ thrmin,
    unsigned* __restrict__ pairs, unsigned* __restrict__ cnt, int cap) {
  __shared__ __attribute__((aligned(16))) _Float16 Bs[2][32 * 256];
  const int tid = threadIdx.x;
  const int w = tid >> 6, lane = tid & 63;
  const int l = lane & 31, hi = lane >> 5;
  const int qt = blockIdx.x >> 3, ks8 = blockIdx.x & 7;
  const int q0 = qt * 256, kbase = ks8 * 1024;
  const int qw = q0 + w * 64;

  f16x8 ah[2][16];
#pragma unroll
  for (int mb = 0; mb < 2; ++mb) {
    const _Float16* pa = xh + (size_t)(qw + mb * 32 + l) * D_ + hi * 8;
#pragma unroll
    for (int k16 = 0; k16 < 16; ++k16)
      ah[mb][k16] = *(const f16x8*)(pa + k16 * 16);
  }

  float tq[2][16];
#pragma unroll
  for (int mb = 0; mb < 2; ++mb)
#pragma unroll
    for (int r = 0; r < 16; ++r) {
      const int row = (r & 3) + 8 * (r >> 2) + 4 * hi;
      tq[mb][r] = dec_sort(thrmin[qw + mb * 32 + row]) + MARGIN;
    }

  auto stage = [&](int ch, int buf) {
    const int kc = kbase + ch * 32;
#pragma unroll
    for (int p = 0; p < 4; ++p) {
      const int c0 = w * 8 + p * 2;
      const int c = c0 + hi;
      const int g = l ^ (c & 31);
      gl_lds16(eh + (size_t)(kc + c) * D_ + g * 8, &Bs[buf][c0 * 256]);
    }
  };
  stage(0, 0);

#pragma unroll 1
  for (int ch = 0; ch < 32; ++ch) {
    const int buf = ch & 1;
    __syncthreads();
    if (ch + 1 < 32) stage(ch + 1, buf ^ 1);
    const int kc = kbase + ch * 32;
    const float c2 = e2h[kc + l];
    f32x16 acc0, acc1;
#pragma unroll
    for (int r = 0; r < 16; ++r) { acc0[r] = 0.f; acc1[r] = 0.f; }
#pragma unroll
    for (int ks = 0; ks < 16; ++ks) {
      f16x8 bh = *(const f16x8*)&Bs[buf][l * 256 + (((ks * 2 + hi) ^ l) * 8)];
      acc0 = __builtin_amdgcn_mfma_f32_32x32x16_f16(ah[0][ks], bh, acc0, 0, 0, 0);
      acc1 = __builtin_amdgcn_mfma_f32_32x32x16_f16(ah[1][ks], bh, acc1, 0, 0, 0);
    }

    // emission test (rare): s~ = c2 - acc <= tq
    bool any = false;
    float sv0[16], sv1[16];
#pragma unroll
    for (int r = 0; r < 16; ++r) {
      sv0[r] = c2 - acc0[r]; any |= (sv0[r] <= tq[0][r]);
      sv1[r] = c2 - acc1[r]; any |= (sv1[r] <= tq[1][r]);
    }
    if (__any(any)) {
      const int k = kc + l;
#pragma unroll
      for (int r = 0; r < 16; ++r) {
        const int row = (r & 3) + 8 * (r >> 2) + 4 * hi;
        if (sv0[r] <= tq[0][r]) {
          unsigned idx = atomicAdd(cnt, 1u);
          if ((int)idx < cap) pairs[idx] = ((unsigned)(qw + row) << 13) | (unsigned)k;
        }
        if (sv1[r] <= tq[1][r]) {
          unsigned idx = atomicAdd(cnt, 1u);
          if ((int)idx < cap) pairs[idx] = ((unsigned)(qw + 32 + row) << 13) | (unsigned)k;
        }
      }
    }
  }
}

// Pass 2: exact fp32 refine of emitted pairs; winner via packed u64 atomicMin.
__global__ __launch_bounds__(256) void pass2_kernel(
    const _Float16* __restrict__ xh, const _Float16* __restrict__ xl,
    const float* __restrict__ e, const float* __restrict__ e2h,
    const unsigned* __restrict__ pairs, const unsigned* __restrict__ cnt,
    int cap, unsigned long long* __restrict__ keys) {
  const int lane = threadIdx.x & 63;
  const int wid = (blockIdx.x * 256 + threadIdx.x) >> 6;
  const int nw = gridDim.x * 4;
  int n = (int)*cnt;
  if (n > cap) n = cap;
  for (int i = wid; i < n; i += nw) {
    unsigned it = pairs[i];
    int q = (int)(it >> 13);
    int k = (int)(it & 8191u);
    f16x4 xh4 = *(const f16x4*)(xh + (size_t)q * D_ + lane * 4);
    f16x4 xl4 = *(const f16x4*)(xl + (size_t)q * D_ + lane * 4);
    float4 ev = *(const float4*)(e + (size_t)k * D_ + lane * 4);
    float p = ((float)xh4[0] + (float)xl4[0]) * ev.x
            + ((float)xh4[1] + (float)xl4[1]) * ev.y
            + ((float)xh4[2] + (float)xl4[2]) * ev.z
            + ((float)xh4[3] + (float)xl4[3]) * ev.w;
#pragma unroll
    for (int xm = 1; xm <= 32; xm <<= 1) p += __shfl_xor(p, xm, 64);
    if (lane == 0) {
      float s = e2h[k] - p;
      unsigned long long key = ((unsigned long long)enc_sort(s) << 32) | (unsigned)k;
      atomicMin(keys + q, key);
    }
  }
}

// Decode: gather 64 code rows coalesced into LDS, transpose, 256B segments out.
__global__ __launch_bounds__(256, 2) void decode_kernel(
    const unsigned long long* __restrict__ keys,
    const float* __restrict__ e, float* __restrict__ out) {
  __shared__ float tile[64][257];
  int b = blockIdx.x >> 6;
  int n0 = (blockIdx.x & 63) * 64;
  int tid = threadIdx.x;
  int w = tid >> 6, lane = tid & 63;
#pragma unroll
  for (int j = 0; j < 16; ++j) {
    int i = w * 16 + j;
    unsigned idx = (unsigned)(keys[(size_t)b * N_ + n0 + i] & 0xFFFFFFFFull);
    float4 v = *(const float4*)(e + (size_t)idx * D_ + lane * 4);
    *(float4*)&tile[i][lane * 4] = v;
  }
  __syncthreads();
  int nq = tid & 15, dr = tid >> 4;
#pragma unroll
  for (int p = 0; p < 16; ++p) {
    int d = dr + p * 16;
    float4 o;
    o.x = tile[nq * 4 + 0][d];
    o.y = tile[nq * 4 + 1][d];
    o.z = tile[nq * 4 + 2][d];
    o.w = tile[nq * 4 + 3][d];
    *(float4*)(out + ((size_t)b * D_ + d) * N_ + n0 + nq * 4) = o;
  }
}

extern "C" void kernel_launch(void* const* d_in, const int* in_sizes, int n_in,
                              void* d_out, int out_size, void* d_ws, size_t ws_size,
                              hipStream_t stream) {
  const float* x = (const float*)d_in[0];
  const float* e = (const float*)d_in[1];
  float* out = (float*)d_out;

  // ws layout: fixed ~20.2 MB + pairs
  char* wp = (char*)d_ws;
  _Float16* xh = (_Float16*)wp;                                  // 8 MB
  _Float16* xl = (_Float16*)(wp + (size_t)Q_ * D_ * 2);          // 8 MB
  _Float16* eh = (_Float16*)(wp + (size_t)Q_ * D_ * 4);          // 4 MB
  char* p2 = wp + (size_t)Q_ * D_ * 4 + (size_t)K_ * D_ * 2;
  float* e2h = (float*)p2;                                       // 32 KB
  unsigned* thrmin = (unsigned*)(p2 + K_ * 4);                   // 64 KB
  unsigned long long* keys = (unsigned long long*)(p2 + K_ * 4 + Q_ * 4);  // 128 KB
  unsigned* cnt = (unsigned*)(p2 + K_ * 4 + Q_ * 4 + Q_ * 8);    // 1 KB slot
  unsigned* pairs = (unsigned*)(p2 + K_ * 4 + Q_ * 4 + Q_ * 8 + 1024);
  size_t fixed = (size_t)((char*)pairs - wp);
  long long capll = ((long long)ws_size - (long long)fixed) / 4;
  if (capll > (1ll << 22)) capll = 1ll << 22;
  if (capll < 1) capll = 1;
  int cap = (int)capll;

  prep_x_kernel<<<dim3(N_ / 64, D_ / 64, B_), 256, 0, stream>>>(x, xh, xl);
  prep_e_kernel<<<K_ / 8, 256, 0, stream>>>(e, eh, e2h, thrmin, keys, cnt);
  pass0_kernel<<<512, 256, 0, stream>>>(xh, eh, e2h, thrmin);
  pass1_kernel<<<512, 256, 0, stream>>>(xh, eh, e2h, thrmin, pairs, cnt, cap);
  pass2_kernel<<<512, 256, 0, stream>>>(xh, xl, e, e2h, pairs, cnt, cap, keys);
  decode_kernel<<<256, 256, 0, stream>>>(keys, e, out);
}